// Round 6
// baseline (32.567 us; speedup 1.0000x reference)
//
#include <hip/hip_runtime.h>
#include <math.h>

// Steerable CNP target prediction — separable-RBF factorization.
//
// out[t,c] = (sum_i Kx[t,i] * sum_j Ky[t,j] * FMc[j,i]) / (Sx[t]*Sy[t])
// Kx[t,i] = exp(-(xt0 - ax[i])^2 / (2 l^2)), channels 2,3 softplus'd first.
//
// Round 6: latency-bound diagnosis -> double TLP. 8 waves/block
// (wave = channel x j-half), j-split keeps FM traffic constant.
// Lean registers (acc 32 + staging 8) to land <= 64 VGPR so 32 waves/CU
// are schedulable. NO forced min-waves (round-3 lesson: forcing -> spill).

#define NA      128
#define TT      8     // targets per block -> 1024 blocks
#define THREADS 512   // 8 waves: c = wid&3, jq = wid>>2

// ---------- pre-kernel: softplus(FM[2:4]) -> sp (2*128*128 floats) ----------
__global__ __launch_bounds__(256)
void softplus_pre(const float* __restrict__ fm, float* __restrict__ sp)
{
    const int idx = blockIdx.x * 256 + threadIdx.x;          // float4 index
    const int n4  = 2 * NA * NA / 4;                         // 8192
    if (idx >= n4) return;
    float4 v = reinterpret_cast<const float4*>(fm + 2 * NA * NA)[idx];
    v.x = (v.x > 15.0f) ? v.x : log1pf(__expf(v.x));
    v.y = (v.y > 15.0f) ? v.y : log1pf(__expf(v.y));
    v.z = (v.z > 15.0f) ? v.z : log1pf(__expf(v.z));
    v.w = (v.w > 15.0f) ? v.w : log1pf(__expf(v.w));
    reinterpret_cast<float4*>(sp)[idx] = v;
}

// ---------- main kernel ----------
__global__ __launch_bounds__(THREADS)
void cnp_main(const float* __restrict__ fm,    // [4][NA][NA]
              const float* __restrict__ sp,    // [2][NA][NA] softplus'd c2,c3
              const float* __restrict__ grid,  // [NA*NA][2]
              const float* __restrict__ xt,    // [T][2]
              const float* __restrict__ lsp,   // [1]
              float* __restrict__ out,         // means [T][2] then sigmas [T][2]
              int n_target, int use_sp)
{
    __shared__ __attribute__((aligned(16))) float Kx[TT * NA];
    __shared__ __attribute__((aligned(16))) float Ky[TT * NA];
    __shared__ float red[4][2][TT];   // (channel, j-half, target)
    __shared__ float sxy[2][TT];

    const int tid  = threadIdx.x;
    const int wid  = tid >> 6;        // 0..7
    const int c    = wid & 3;         // channel
    const int jq   = wid >> 2;        // wave's j-half (0/1)
    const int lane = tid & 63;
    const int jh   = lane >> 5;       // j-quarter bit within wave
    const int ig   = lane & 31;       // i-group
    const int i4   = ig * 4;          // this thread's 4 i-columns
    const int t0   = blockIdx.x * TT;

    const float l      = lsp[0];
    const float inv2l2 = 0.5f / (l * l);

    // ---- phase 0: separable kernel rows into LDS ----
    // grid[g] = (ax[g>>7], ax[g&127])  =>  ax[j] = grid[j*2+1]
    for (int k = tid; k < TT * NA; k += THREADS) {
        const int t = k >> 7;
        const int j = k & 127;
        int tg = t0 + t; if (tg >= n_target) tg = n_target - 1;
        const float ax = grid[j * 2 + 1];
        const float dx = xt[tg * 2 + 0] - ax;
        const float dy = xt[tg * 2 + 1] - ax;
        Kx[k] = __expf(-dx * dx * inv2l2);
        Ky[k] = __expf(-dy * dy * inv2l2);
    }
    __syncthreads();

    // ---- phase 1: V[t][4i] = sum_{j in my 32-row window} Ky[t,j]*FMc[j,i] ----
    const float* src = (c < 2 || !use_sp) ? (fm + c * NA * NA)
                                          : (sp + (c - 2) * NA * NA);
    const bool do_sp_inline = (!use_sp) && (c >= 2);

    float4 v0, v1, v2, v3, v4, v5, v6, v7;
    v0 = v1 = v2 = v3 = v4 = v5 = v6 = v7 = make_float4(0.f, 0.f, 0.f, 0.f);

    const int j0 = (jq * 2 + jh) * 32;        // 32-row window per (wave, jh)
    const float* base = src + j0 * NA + i4;

#pragma unroll 2
    for (int g = 0; g < 16; ++g) {
        const int jj = 2 * g;
        float4 f0 = *reinterpret_cast<const float4*>(&base[(jj + 0) * NA]);
        float4 f1 = *reinterpret_cast<const float4*>(&base[(jj + 1) * NA]);
        if (do_sp_inline) {   // fallback only if ws too small (dead in practice)
#define SP1(z) z = (z > 15.0f) ? z : log1pf(__expf(z))
            SP1(f0.x); SP1(f0.y); SP1(f0.z); SP1(f0.w);
            SP1(f1.x); SP1(f1.y); SP1(f1.z); SP1(f1.w);
#undef SP1
        }
#define STEP(T, V)                                                             \
        {                                                                      \
            const float2 k2 = *reinterpret_cast<const float2*>(&Ky[(T) * NA + j0 + jj]); \
            V.x = fmaf(k2.x, f0.x, fmaf(k2.y, f1.x, V.x));                     \
            V.y = fmaf(k2.x, f0.y, fmaf(k2.y, f1.y, V.y));                     \
            V.z = fmaf(k2.x, f0.z, fmaf(k2.y, f1.z, V.z));                     \
            V.w = fmaf(k2.x, f0.w, fmaf(k2.y, f1.w, V.w));                     \
        }
        STEP(0, v0) STEP(1, v1) STEP(2, v2) STEP(3, v3)
        STEP(4, v4) STEP(5, v5) STEP(6, v6) STEP(7, v7)
#undef STEP
    }

    // ---- phase 2: apply Kx, 64-lane reduce -> red[c][jq][t] ----
#define RED(T, V)                                                              \
    {                                                                          \
        const float4 kx4 = *reinterpret_cast<const float4*>(&Kx[(T) * NA + i4]); \
        float w = fmaf(kx4.x, V.x, fmaf(kx4.y, V.y, fmaf(kx4.z, V.z, kx4.w * V.w))); \
        w += __shfl_xor(w, 1);  w += __shfl_xor(w, 2);  w += __shfl_xor(w, 4); \
        w += __shfl_xor(w, 8);  w += __shfl_xor(w, 16); w += __shfl_xor(w, 32); \
        if (lane == 0) red[c][jq][(T)] = w;                                    \
    }
    RED(0, v0) RED(1, v1) RED(2, v2) RED(3, v3)
    RED(4, v4) RED(5, v5) RED(6, v6) RED(7, v7)
#undef RED

    // ---- Sx on wave 0, Sy on wave 4 (independent waves, 32-wide per jh) ----
    if (wid == 0 || wid == 4) {
        const float* kb = jq ? Ky : Kx;   // wid 0 -> Kx, wid 4 -> Ky
#define SRED(T)                                                                \
        {                                                                      \
            const float4 q = *reinterpret_cast<const float4*>(&kb[(T) * NA + i4]); \
            float u = (q.x + q.y) + (q.z + q.w);                               \
            u += __shfl_xor(u, 1); u += __shfl_xor(u, 2); u += __shfl_xor(u, 4); \
            u += __shfl_xor(u, 8); u += __shfl_xor(u, 16); u += __shfl_xor(u, 32); \
            if (lane == 0) sxy[jq][(T)] = u * 0.5f;   /* jh halves both summed */ \
        }
        SRED(0) SRED(1) SRED(2) SRED(3) SRED(4) SRED(5) SRED(6) SRED(7)
#undef SRED
    }
    __syncthreads();

    // ---- phase 3: combine j-halves, normalize, write (32 outputs) ----
    if (tid < 4 * TT) {
        const int t  = tid & (TT - 1);
        const int cc = tid >> 3;            // requires TT == 8
        const int tg = t0 + t;
        if (tg < n_target) {
            const float numer = red[cc][0][t] + red[cc][1][t];
            const float val = numer / (sxy[0][t] * sxy[1][t]);
            if (cc < 2) out[tg * 2 + cc] = val;                        // means
            else        out[n_target * 2 + tg * 2 + (cc - 2)] = val;   // sigmas
        }
    }
}

extern "C" void kernel_launch(void* const* d_in, const int* in_sizes, int n_in,
                              void* d_out, int out_size, void* d_ws, size_t ws_size,
                              hipStream_t stream) {
    const float* fm   = (const float*)d_in[0];
    const float* grid = (const float*)d_in[1];
    const float* xt   = (const float*)d_in[2];
    const float* lsp  = (const float*)d_in[3];
    float* out = (float*)d_out;
    float* sp  = (float*)d_ws;

    const int n_target = in_sizes[2] / 2;                 // 8192
    const size_t sp_bytes = (size_t)2 * NA * NA * sizeof(float);
    const int use_sp = (ws_size >= sp_bytes) ? 1 : 0;

    if (use_sp) {
        const int n4 = 2 * NA * NA / 4;                   // 8192 float4s
        hipLaunchKernelGGL(softplus_pre, dim3((n4 + 255) / 256), dim3(256), 0, stream,
                           fm, sp);
    }
    const int blocks = (n_target + TT - 1) / TT;          // 1024
    hipLaunchKernelGGL(cnp_main, dim3(blocks), dim3(THREADS), 0, stream,
                       fm, sp, grid, xt, lsp, out, n_target, use_sp);
}